// Round 3
// baseline (933.642 us; speedup 1.0000x reference)
//
#include <hip/hip_runtime.h>
#include <cstdint>
#include <cstddef>

// ---------------- constants ----------------
#define N_TOK   16384      // 4 * 4096
#define D_TOTAL 2048
#define N_HEAD  16
#define D_HEAD  128
#define HID     512
#define MT      64         // tokens per block in fused kernel
#define RMS_EPS 1.1920929e-07f   // np.finfo(np.float32).eps

typedef __attribute__((ext_vector_type(8)))  short  short8;
typedef __attribute__((ext_vector_type(4)))  float  float4_t;
typedef __attribute__((ext_vector_type(16))) float  f32x16;
typedef __attribute__((ext_vector_type(2)))  unsigned int uint2_t;

// ---------------- bf16 helpers ----------------
__device__ __forceinline__ unsigned short f2bf(float f) {
    union { float f; unsigned int i; } v; v.f = f;
    unsigned int b = v.i;
    b += 0x7FFFu + ((b >> 16) & 1u);      // round-to-nearest-even
    return (unsigned short)(b >> 16);
}

// packed fp32x2 -> bf16x2 (RNE, same rounding as f2bf); no builtin on gfx950
__device__ __forceinline__ unsigned int cvt_pk_bf16(float lo, float hi) {
    unsigned int r;
    asm("v_cvt_pk_bf16_f32 %0, %1, %2" : "=v"(r) : "v"(lo), "v"(hi));
    return r;
}

// single-instruction 2^x (avoids libm exp2f edge-case fixup VALU)
__device__ __forceinline__ float fast_exp2(float x) {
#if __has_builtin(__builtin_amdgcn_exp2f)
    return __builtin_amdgcn_exp2f(x);
#else
    return exp2f(x);
#endif
}

// Exact-GELU via Abramowitz-Stegun 7.1.26 erf (|eps| <= 1.5e-7), branchless.
// gelu(x) = 0.5x(1+erf(x/sqrt2)) = 0.5x + 0.5|x|*erf(|x|/sqrt2)  (sign-free)
__device__ __forceinline__ float gelu_exact(float x) {
    float ax = fabsf(x);
    // t = 1/(1 + 0.3275911*|x|/sqrt2) = 1/(1 + 0.23164193*|x|)
    float t  = __builtin_amdgcn_rcpf(fmaf(0.23164193f, ax, 1.0f));
    float poly = fmaf(fmaf(fmaf(fmaf(1.061405429f, t, -1.453152027f),
                               t, 1.421413741f), t, -0.284496736f),
                      t, 0.254829592f) * t;
    // exp(-z^2) = exp2(x^2 * -0.72134752)
    float e    = fast_exp2(x * x * -0.72134752f);
    float erfa = fmaf(-poly, e, 1.0f);          // erf(|z|)
    return fmaf(0.5f * ax, erfa, 0.5f * x);
}

// ---------------- kernel 1: fused prep (rms scales + all weight transposes) ----
// blocks [0,4096): per-token inv-RMS (one wave per token).
// blocks [4096,6656): 64x64 transpose+cast tiles for w0/w1/w2/w3.
__global__ __launch_bounds__(256) void prep_kernel(
    const float* __restrict__ x, float* __restrict__ scale,
    const float* __restrict__ w0, const float* __restrict__ w1,
    const float* __restrict__ w2, const float* __restrict__ w3,
    const float* __restrict__ gw,
    unsigned short* __restrict__ wt0, unsigned short* __restrict__ wt1,
    unsigned short* __restrict__ wt2, unsigned short* __restrict__ wt3)
{
    int b = blockIdx.x;
    if (b < 4096) {
        // ---- RMS scale ----
        const int lane  = threadIdx.x & 63;
        const int wv    = threadIdx.x >> 6;
        const int token = b * 4 + wv;
        const float* xp = x + (size_t)token * D_TOTAL;
        float s = 0.0f;
#pragma unroll
        for (int j = 0; j < 8; ++j) {
            float4 v = *(const float4*)(xp + (size_t)(j * 64 + lane) * 4);
            s += v.x * v.x + v.y * v.y + v.z * v.z + v.w * v.w;
        }
#pragma unroll
        for (int off = 32; off > 0; off >>= 1) s += __shfl_down(s, off, 64);
        if (lane == 0)
            scale[token] = rsqrtf(s * (1.0f / (float)D_TOTAL) + RMS_EPS);
        return;
    }

    // ---- transpose+cast: W[h][K][N] fp32 -> WT[h][N][K] bf16 ----
    b -= 4096;
    const float* in; unsigned short* out; int K, N; const float* gm = nullptr;
    if      (b <  256) { in = w0; out = wt0; K = 128; N = 512; gm = gw; }
    else if (b < 1280) { in = w1; out = wt1; K = 512; N = 512; b -= 256; }
    else if (b < 2304) { in = w2; out = wt2; K = 512; N = 512; b -= 1280; }
    else               { in = w3; out = wt3; K = 512; N = 128; b -= 2304; }

    const int ktiles = K >> 6, ntiles = N >> 6;
    const int h   = b / (ktiles * ntiles);
    const int rem = b % (ktiles * ntiles);
    const int kt  = rem / ntiles, nt = rem % ntiles;

    const float* src = in + (size_t)h * K * N + (size_t)(kt * 64) * N + nt * 64;
    unsigned short* dst = out + (size_t)h * N * K + (size_t)(nt * 64) * K + kt * 64;

    __shared__ unsigned short tile[64][72];

#pragma unroll
    for (int p = 0; p < 2; ++p) {
        int gi = threadIdx.x + p * 256;
        int r  = gi >> 3;                 // row within tile = k offset
        int gc = (gi & 7) * 8;
        float mul = 1.0f;
        if (gm) mul = gm[(size_t)h * K + kt * 64 + r];
        float4 a  = *(const float4*)(src + (size_t)r * N + gc);
        float4 b4 = *(const float4*)(src + (size_t)r * N + gc + 4);
        unsigned short tmp[8];
        tmp[0]=f2bf(a.x*mul);  tmp[1]=f2bf(a.y*mul);  tmp[2]=f2bf(a.z*mul);  tmp[3]=f2bf(a.w*mul);
        tmp[4]=f2bf(b4.x*mul); tmp[5]=f2bf(b4.y*mul); tmp[6]=f2bf(b4.z*mul); tmp[7]=f2bf(b4.w*mul);
        *(uint4*)&tile[r][gc] = *(const uint4*)tmp;
    }
    __syncthreads();
#pragma unroll
    for (int p = 0; p < 2; ++p) {
        int gi  = threadIdx.x + p * 256;
        int r2  = gi >> 3;
        int gc2 = (gi & 7) * 8;
        unsigned short tmp[8];
#pragma unroll
        for (int j = 0; j < 8; ++j) tmp[j] = tile[gc2 + j][r2];
        *(uint4*)(dst + (size_t)r2 * K + gc2) = *(const uint4*)tmp;
    }
}

// ---------------- fused chain GEMM stage (operand-swapped, 32x32x16) --------
// D = mfma_32x32x16(A = W^T frag, B = X^T frag):
//   A (weights):     lane holds n-row = nbase+nt*32+(l&31), 8 k-contig at (l>>5)*8
//   B (activations): lane holds token = mt0+mt*32+(l&31),   8 k-contig at (l>>5)*8
//   D: col = token (l&31), n = (reg&3)+8*(reg>>2)+4*(l>>5)  -> 4 groups of 4
//      consecutive n per lane.
// Half the MFMA instrs and half the per-kstep operand regs vs 16x16x32.
// LDS b-address: granule g = ks*2+h, stored at g ^ (row&7):
//   byte(ks) = vb ^ (ks<<5), vb = row*1024 + 16*((row&6 of swz) | (h^(row&1)))
template<int K, int MTT, int NT>
__device__ __forceinline__ void stage_gemm32(
    const unsigned short* __restrict__ sA,      // LDS, 64 x 512 bf16, XOR-swizzled
    const unsigned short* __restrict__ wt,      // global bf16, [N][K] this head
    int lane, int mt0, int nbase, f32x16 acc[MTT][NT])
{
#pragma unroll
    for (int mt = 0; mt < MTT; ++mt)
#pragma unroll
        for (int nt = 0; nt < NT; ++nt)
#pragma unroll
            for (int i = 0; i < 16; ++i) acc[mt][nt][i] = 0.0f;

    const int r31 = lane & 31;
    const int h   = lane >> 5;            // 0/1: k-half selector

    // A (weight) row base pointers: n fixed across the K loop
    const char* arow[NT];
#pragma unroll
    for (int nt = 0; nt < NT; ++nt)
        arow[nt] = (const char*)(wt + (size_t)(nbase + nt * 32 + r31) * K + h * 8);

    // B (activation) swizzled byte-address bases: addr(ks) = vb ^ (ks<<5)
    const char* sab = (const char*)sA;
    unsigned int vb[MTT];
#pragma unroll
    for (int mt = 0; mt < MTT; ++mt) {
        unsigned int row = (unsigned)(mt0 + mt * 32 + r31);
        unsigned int r7  = row & 7u;
        unsigned int g0  = (r7 & 6u) | ((unsigned)h ^ (r7 & 1u));
        vb[mt] = row * 1024u + (g0 << 4);
    }

#pragma unroll
    for (int ks = 0; ks < K / 16; ++ks) {
        short8 a[NT], b[MTT];
#pragma unroll
        for (int nt = 0; nt < NT; ++nt)
            a[nt] = *(const short8*)(arow[nt] + ks * 32);
#pragma unroll
        for (int mt = 0; mt < MTT; ++mt)
            b[mt] = *(const short8*)(sab + (vb[mt] ^ (unsigned)(ks << 5)));
#pragma unroll
        for (int mt = 0; mt < MTT; ++mt)
#pragma unroll
            for (int nt = 0; nt < NT; ++nt)
                acc[mt][nt] = __builtin_amdgcn_mfma_f32_32x32x16_bf16(
                    a[nt], b[mt], acc[mt][nt], 0, 0, 0);
    }
}

// gelu + pack + swizzled LDS writeback for 32x32 D tiles.
// reg r = 4*g + i: n = nbase+nt*32 + 8*g + 4*h + i  -> per group g: 4 gelu,
// 2 cvt_pk, one 8B LDS write (within one 16B swizzle granule since 4h&7 in {0,4}).
template<int MTT, int NT>
__device__ __forceinline__ void epi_gelu32(
    unsigned short* __restrict__ sAct, int lane, int mt0, int nbase,
    f32x16 acc[MTT][NT])
{
    const int r31 = lane & 31;
    const int h   = lane >> 5;
#pragma unroll
    for (int mt = 0; mt < MTT; ++mt) {
        const int tok = mt0 + mt * 32 + r31;
        const unsigned int rbase = (unsigned)tok * HID;
        const int tk7 = tok & 7;
#pragma unroll
        for (int nt = 0; nt < NT; ++nt)
#pragma unroll
            for (int g = 0; g < 4; ++g) {
                const int col = nbase + nt * 32 + 8 * g + 4 * h;
                float g0 = gelu_exact(acc[mt][nt][4 * g + 0]);
                float g1 = gelu_exact(acc[mt][nt][4 * g + 1]);
                float g2 = gelu_exact(acc[mt][nt][4 * g + 2]);
                float g3 = gelu_exact(acc[mt][nt][4 * g + 3]);
                uint2_t v;
                v.x = cvt_pk_bf16(g0, g1);
                v.y = cvt_pk_bf16(g2, g3);
                const int gsw = (col >> 3) ^ tk7;
                *(uint2_t*)&sAct[rbase + gsw * 8 + (col & 7)] = v;
            }
    }
}

// ---------------- kernel 3: fused per-(head, token-tile) chain ----------------
// 512 threads / 8 waves. Stages 1-3: each wave owns a 64-token x 64-col tile
// (2x2 32x32 MFMA tiles). Stage 4: one 32x32 tile per wave (8 tiles total).
// 64 KiB LDS -> 2 blocks/CU -> 16 waves/CU.
__global__ __launch_bounds__(512, 4) void fused_chain_kernel(
    const float*          __restrict__ x,     // fp32
    const float*          __restrict__ scale,
    const unsigned short* __restrict__ wt0,   // [H][512][128] bf16 (g pre-folded)
    const unsigned short* __restrict__ wt1,   // [H][512][512] bf16
    const unsigned short* __restrict__ wt2,   // [H][512][512] bf16
    const unsigned short* __restrict__ wt3,   // [H][128][512] bf16
    float*                __restrict__ out)   // fp32
{
    __shared__ unsigned short sAct[MT * HID];   // 64 KiB

    const int tid  = threadIdx.x;
    const int lane = tid & 63;
    const int wv   = tid >> 6;            // 0..7
    const int bx    = blockIdx.x;
    const int xcd   = bx & 7;
    const int local = bx >> 3;            // 0..511
    const int head  = xcd * 2 + (local >> 8);
    const int tile  = local & 255;
    const int tok0  = tile * MT;

    // ---- stage 0: normalized x-slice (bf16) into cols [0,128) of sAct ----
    // (g is folded into wt0 at transpose time)
#pragma unroll
    for (int p = 0; p < 2; ++p) {
        int gi = tid + p * 512;          // 0..1023 granules (64 rows x 16)
        int r  = gi >> 4;
        int gc = gi & 15;
        int token = tok0 + r;
        const float* xp = x + (size_t)token * D_TOTAL + head * D_HEAD + gc * 8;
        float4 xa = *(const float4*)(xp);
        float4 xb = *(const float4*)(xp + 4);
        float s = scale[token];
        unsigned int u[4];
        u[0] = cvt_pk_bf16(xa.x * s, xa.y * s);
        u[1] = cvt_pk_bf16(xa.z * s, xa.w * s);
        u[2] = cvt_pk_bf16(xb.x * s, xb.y * s);
        u[3] = cvt_pk_bf16(xb.z * s, xb.w * s);
        int gsw = gc ^ (r & 7);
        *(uint4*)&sAct[r * HID + gsw * 8] = *(const uint4*)u;
    }
    __syncthreads();

    f32x16 acc[2][2];
    const int nb = wv * 64;              // this wave's N-chunk for stages 1-3

    // ---- stage 1: K=128 -> N=512 ----
    stage_gemm32<128, 2, 2>(sAct, wt0 + (size_t)head * HID * D_HEAD, lane, 0, nb, acc);
    __syncthreads();
    epi_gelu32<2, 2>(sAct, lane, 0, nb, acc);
    __syncthreads();

    // ---- stage 2: K=512 -> N=512 ----
    stage_gemm32<512, 2, 2>(sAct, wt1 + (size_t)head * HID * HID, lane, 0, nb, acc);
    __syncthreads();
    epi_gelu32<2, 2>(sAct, lane, 0, nb, acc);
    __syncthreads();

    // ---- stage 3: K=512 -> N=512 ----
    stage_gemm32<512, 2, 2>(sAct, wt2 + (size_t)head * HID * HID, lane, 0, nb, acc);
    __syncthreads();
    epi_gelu32<2, 2>(sAct, lane, 0, nb, acc);
    __syncthreads();

    // ---- stage 4: K=512 -> N=128, one 32x32 tile per wave, straight to global ----
    const int mt4 = (wv >> 2) * 32;      // token 32-block
    const int nt4 = (wv & 3) * 32;       // col 32-block
    f32x16 acc2[1][1];
    stage_gemm32<512, 1, 1>(sAct, wt3 + (size_t)head * D_HEAD * HID, lane, mt4, nt4, acc2);

    // D: col = token (l&31), n = 8*g + 4*h + i -> float4 store per group.
    const int r31 = lane & 31;
    const int h   = lane >> 5;
    const int token = tok0 + mt4 + r31;
#pragma unroll
    for (int g = 0; g < 4; ++g) {
        const int col = head * D_HEAD + nt4 + 8 * g + 4 * h;
        float4_t v;
        v[0] = acc2[0][0][4 * g + 0];
        v[1] = acc2[0][0][4 * g + 1];
        v[2] = acc2[0][0][4 * g + 2];
        v[3] = acc2[0][0][4 * g + 3];
        *(float4_t*)&out[(size_t)token * D_TOTAL + col] = v;
    }
}

// ---------------- host launcher ----------------
extern "C" void kernel_launch(void* const* d_in, const int* in_sizes, int n_in,
                              void* d_out, int out_size, void* d_ws, size_t ws_size,
                              hipStream_t stream)
{
    const float* x  = (const float*)d_in[0];
    const float* gw = (const float*)d_in[1];
    const float* w0 = (const float*)d_in[2];
    const float* w1 = (const float*)d_in[3];
    const float* w2 = (const float*)d_in[4];
    const float* w3 = (const float*)d_in[5];
    float* out = (float*)d_out;

    // workspace layout
    float* scale = (float*)d_ws;                                   // 64 KB
    unsigned short* wt0 = (unsigned short*)((char*)d_ws + 65536);  // [16][512][128]
    unsigned short* wt1 = wt0 + (size_t)N_HEAD * HID * D_HEAD;     // [16][512][512]
    unsigned short* wt2 = wt1 + (size_t)N_HEAD * HID * HID;        // [16][512][512]
    unsigned short* wt3 = wt2 + (size_t)N_HEAD * HID * HID;        // [16][128][512]

    // one prep launch: rms scales (4096 blocks) + 2560 transpose tiles
    prep_kernel<<<4096 + 2560, 256, 0, stream>>>(
        x, scale, w0, w1, w2, w3, gw, wt0, wt1, wt2, wt3);

    fused_chain_kernel<<<N_HEAD * (N_TOK / MT), 512, 0, stream>>>(
        x, scale, wt0, wt1, wt2, wt3, out);
}

// Round 4
// 824.915 us; speedup vs baseline: 1.1318x; 1.1318x over previous
//
#include <hip/hip_runtime.h>
#include <cstdint>
#include <cstddef>

// ---------------- constants ----------------
#define N_TOK   16384      // 4 * 4096
#define D_TOTAL 2048
#define N_HEAD  16
#define D_HEAD  128
#define HID     512
#define MT      128        // tokens per block in fused kernel (128 KiB sAct)
#define RMS_EPS 1.1920929e-07f   // np.finfo(np.float32).eps

typedef __attribute__((ext_vector_type(8)))  short  short8;
typedef __attribute__((ext_vector_type(4)))  float  float4_t;
typedef __attribute__((ext_vector_type(16))) float  f32x16;
typedef __attribute__((ext_vector_type(2)))  unsigned int uint2_t;

// ---------------- bf16 helpers ----------------
__device__ __forceinline__ unsigned short f2bf(float f) {
    union { float f; unsigned int i; } v; v.f = f;
    unsigned int b = v.i;
    b += 0x7FFFu + ((b >> 16) & 1u);      // round-to-nearest-even
    return (unsigned short)(b >> 16);
}

// packed fp32x2 -> bf16x2 (RNE, same rounding as f2bf); no builtin on gfx950
__device__ __forceinline__ unsigned int cvt_pk_bf16(float lo, float hi) {
    unsigned int r;
    asm("v_cvt_pk_bf16_f32 %0, %1, %2" : "=v"(r) : "v"(lo), "v"(hi));
    return r;
}

// single-instruction 2^x (avoids libm exp2f edge-case fixup VALU)
__device__ __forceinline__ float fast_exp2(float x) {
#if __has_builtin(__builtin_amdgcn_exp2f)
    return __builtin_amdgcn_exp2f(x);
#else
    return exp2f(x);
#endif
}

// Exact-GELU via Abramowitz-Stegun 7.1.26 erf (|eps| <= 1.5e-7), branchless.
// gelu(x) = 0.5x(1+erf(x/sqrt2)) = 0.5x + 0.5|x|*erf(|x|/sqrt2)  (sign-free)
__device__ __forceinline__ float gelu_exact(float x) {
    float ax = fabsf(x);
    float t  = __builtin_amdgcn_rcpf(fmaf(0.23164193f, ax, 1.0f));
    float poly = fmaf(fmaf(fmaf(fmaf(1.061405429f, t, -1.453152027f),
                               t, 1.421413741f), t, -0.284496736f),
                      t, 0.254829592f) * t;
    float e    = fast_exp2(x * x * -0.72134752f);
    float erfa = fmaf(-poly, e, 1.0f);          // erf(|z|)
    return fmaf(0.5f * ax, erfa, 0.5f * x);
}

// ---------------- kernel 1: fused prep (rms scales + all weight transposes) ----
// blocks [0,4096): per-token inv-RMS (one wave per token).
// blocks [4096,6656): 64x64 transpose+cast tiles for w0/w1/w2/w3.
__global__ __launch_bounds__(256) void prep_kernel(
    const float* __restrict__ x, float* __restrict__ scale,
    const float* __restrict__ w0, const float* __restrict__ w1,
    const float* __restrict__ w2, const float* __restrict__ w3,
    const float* __restrict__ gw,
    unsigned short* __restrict__ wt0, unsigned short* __restrict__ wt1,
    unsigned short* __restrict__ wt2, unsigned short* __restrict__ wt3)
{
    int b = blockIdx.x;
    if (b < 4096) {
        const int lane  = threadIdx.x & 63;
        const int wv    = threadIdx.x >> 6;
        const int token = b * 4 + wv;
        const float* xp = x + (size_t)token * D_TOTAL;
        float s = 0.0f;
#pragma unroll
        for (int j = 0; j < 8; ++j) {
            float4 v = *(const float4*)(xp + (size_t)(j * 64 + lane) * 4);
            s += v.x * v.x + v.y * v.y + v.z * v.z + v.w * v.w;
        }
#pragma unroll
        for (int off = 32; off > 0; off >>= 1) s += __shfl_down(s, off, 64);
        if (lane == 0)
            scale[token] = rsqrtf(s * (1.0f / (float)D_TOTAL) + RMS_EPS);
        return;
    }

    // ---- transpose+cast: W[h][K][N] fp32 -> WT[h][N][K] bf16 ----
    b -= 4096;
    const float* in; unsigned short* out; int K, N; const float* gm = nullptr;
    if      (b <  256) { in = w0; out = wt0; K = 128; N = 512; gm = gw; }
    else if (b < 1280) { in = w1; out = wt1; K = 512; N = 512; b -= 256; }
    else if (b < 2304) { in = w2; out = wt2; K = 512; N = 512; b -= 1280; }
    else               { in = w3; out = wt3; K = 512; N = 128; b -= 2304; }

    const int ktiles = K >> 6, ntiles = N >> 6;
    const int h   = b / (ktiles * ntiles);
    const int rem = b % (ktiles * ntiles);
    const int kt  = rem / ntiles, nt = rem % ntiles;

    const float* src = in + (size_t)h * K * N + (size_t)(kt * 64) * N + nt * 64;
    unsigned short* dst = out + (size_t)h * N * K + (size_t)(nt * 64) * K + kt * 64;

    __shared__ unsigned short tile[64][72];

#pragma unroll
    for (int p = 0; p < 2; ++p) {
        int gi = threadIdx.x + p * 256;
        int r  = gi >> 3;                 // row within tile = k offset
        int gc = (gi & 7) * 8;
        float mul = 1.0f;
        if (gm) mul = gm[(size_t)h * K + kt * 64 + r];
        float4 a  = *(const float4*)(src + (size_t)r * N + gc);
        float4 b4 = *(const float4*)(src + (size_t)r * N + gc + 4);
        unsigned short tmp[8];
        tmp[0]=f2bf(a.x*mul);  tmp[1]=f2bf(a.y*mul);  tmp[2]=f2bf(a.z*mul);  tmp[3]=f2bf(a.w*mul);
        tmp[4]=f2bf(b4.x*mul); tmp[5]=f2bf(b4.y*mul); tmp[6]=f2bf(b4.z*mul); tmp[7]=f2bf(b4.w*mul);
        *(uint4*)&tile[r][gc] = *(const uint4*)tmp;
    }
    __syncthreads();
#pragma unroll
    for (int p = 0; p < 2; ++p) {
        int gi  = threadIdx.x + p * 256;
        int r2  = gi >> 3;
        int gc2 = (gi & 7) * 8;
        unsigned short tmp[8];
#pragma unroll
        for (int j = 0; j < 8; ++j) tmp[j] = tile[gc2 + j][r2];
        *(uint4*)(dst + (size_t)r2 * K + gc2) = *(const uint4*)tmp;
    }
}

// ---------------- fused chain GEMM stage (operand-swapped, 32x32x16) --------
// D = mfma_32x32x16(A = W^T frag, B = X^T frag):
//   A (weights):     lane holds n-row = nbase+nt*32+(l&31), 8 k-contig at (l>>5)*8
//   B (activations): lane holds token = mt0+mt*32+(l&31),   8 k-contig at (l>>5)*8
//   D: col = token (l&31), n = (reg&3)+8*(reg>>2)+4*(l>>5)
// Explicit depth-2 software pipeline on the A (global/L2) loads: apf[2][NT]
// rotated by compile-time ks&1 under full unroll (no copies, no scratch).
template<int K, int MTT, int NT>
__device__ __forceinline__ void stage_gemm32(
    const unsigned short* __restrict__ sA,      // LDS, MT x 512 bf16, XOR-swizzled
    const unsigned short* __restrict__ wt,      // global bf16, [N][K] this head
    int lane, int mt0, int nbase, f32x16 acc[MTT][NT])
{
    constexpr int NK = K / 16;
#pragma unroll
    for (int mt = 0; mt < MTT; ++mt)
#pragma unroll
        for (int nt = 0; nt < NT; ++nt)
#pragma unroll
            for (int i = 0; i < 16; ++i) acc[mt][nt][i] = 0.0f;

    const int r31 = lane & 31;
    const int h   = lane >> 5;            // 0/1: k-half selector

    // A (weight) row base pointers: n fixed across the K loop
    const char* arow[NT];
#pragma unroll
    for (int nt = 0; nt < NT; ++nt)
        arow[nt] = (const char*)(wt + (size_t)(nbase + nt * 32 + r31) * K + h * 8);

    // B (activation) swizzled byte-address bases: addr(ks) = vb ^ (ks<<5)
    const char* sab = (const char*)sA;
    unsigned int vb[MTT];
#pragma unroll
    for (int mt = 0; mt < MTT; ++mt) {
        unsigned int row = (unsigned)(mt0 + mt * 32 + r31);
        unsigned int r7  = row & 7u;
        unsigned int g0  = (r7 & 6u) | ((unsigned)h ^ (r7 & 1u));
        vb[mt] = row * 1024u + (g0 << 4);
    }

    // prologue: prefetch A for ks = 0, 1
    short8 apf[2][NT];
#pragma unroll
    for (int nt = 0; nt < NT; ++nt) apf[0][nt] = *(const short8*)(arow[nt]);
#pragma unroll
    for (int nt = 0; nt < NT; ++nt) apf[1][nt] = *(const short8*)(arow[nt] + 32);

#pragma unroll
    for (int ks = 0; ks < NK; ++ks) {
        short8 a[NT];
#pragma unroll
        for (int nt = 0; nt < NT; ++nt) a[nt] = apf[ks & 1][nt];
        if (ks + 2 < NK) {
#pragma unroll
            for (int nt = 0; nt < NT; ++nt)
                apf[ks & 1][nt] = *(const short8*)(arow[nt] + (ks + 2) * 32);
        }
        short8 b[MTT];
#pragma unroll
        for (int mt = 0; mt < MTT; ++mt)
            b[mt] = *(const short8*)(sab + (vb[mt] ^ (unsigned)(ks << 5)));
#pragma unroll
        for (int mt = 0; mt < MTT; ++mt)
#pragma unroll
            for (int nt = 0; nt < NT; ++nt)
                acc[mt][nt] = __builtin_amdgcn_mfma_f32_32x32x16_bf16(
                    a[nt], b[mt], acc[mt][nt], 0, 0, 0);
    }
}

// gelu + pack + swizzled LDS writeback for 32x32 D tiles.
template<int MTT, int NT>
__device__ __forceinline__ void epi_gelu32(
    unsigned short* __restrict__ sAct, int lane, int mt0, int nbase,
    f32x16 acc[MTT][NT])
{
    const int r31 = lane & 31;
    const int h   = lane >> 5;
#pragma unroll
    for (int mt = 0; mt < MTT; ++mt) {
        const int tok = mt0 + mt * 32 + r31;
        const unsigned int rbase = (unsigned)tok * HID;
        const int tk7 = tok & 7;
#pragma unroll
        for (int nt = 0; nt < NT; ++nt)
#pragma unroll
            for (int g = 0; g < 4; ++g) {
                const int col = nbase + nt * 32 + 8 * g + 4 * h;
                float g0 = gelu_exact(acc[mt][nt][4 * g + 0]);
                float g1 = gelu_exact(acc[mt][nt][4 * g + 1]);
                float g2 = gelu_exact(acc[mt][nt][4 * g + 2]);
                float g3 = gelu_exact(acc[mt][nt][4 * g + 3]);
                uint2_t v;
                v.x = cvt_pk_bf16(g0, g1);
                v.y = cvt_pk_bf16(g2, g3);
                const int gsw = (col >> 3) ^ tk7;
                *(uint2_t*)&sAct[rbase + gsw * 8 + (col & 7)] = v;
            }
    }
}

// ---------------- kernel 3: fused per-(head, token-tile) chain ----------------
// MT=128 tokens/block, 512 threads / 8 waves, 128 KiB LDS -> 1 block/CU,
// 2 waves/SIMD with a 256-reg unified budget (acc 128 AGPR + ~100 arch VGPR
// for the depth-2 A pipeline). Weight L2 traffic per FLOP is HALF of MT=64.
// Stages 1-3: wave owns 128 tok x 64 cols (4x2 32x32 tiles). Stage 4: 2 tiles.
__global__ __launch_bounds__(512, 2) void fused_chain_kernel(
    const float*          __restrict__ x,     // fp32
    const float*          __restrict__ scale,
    const unsigned short* __restrict__ wt0,   // [H][512][128] bf16 (g pre-folded)
    const unsigned short* __restrict__ wt1,   // [H][512][512] bf16
    const unsigned short* __restrict__ wt2,   // [H][512][512] bf16
    const unsigned short* __restrict__ wt3,   // [H][128][512] bf16
    float*                __restrict__ out)   // fp32
{
    __shared__ unsigned short sAct[MT * HID];   // 128 KiB

    const int tid  = threadIdx.x;
    const int lane = tid & 63;
    const int wv   = tid >> 6;            // 0..7
    const int bx    = blockIdx.x;
    const int xcd   = bx & 7;
    const int local = bx >> 3;            // 0..255
    const int head  = xcd * 2 + (local >> 7);
    const int tile  = local & 127;
    const int tok0  = tile * MT;

    // ---- stage 0: normalized x-slice (bf16) into cols [0,128) of sAct ----
#pragma unroll
    for (int p = 0; p < 4; ++p) {
        int gi = tid + p * 512;          // 0..2047 granules (128 rows x 16)
        int r  = gi >> 4;
        int gc = gi & 15;
        int token = tok0 + r;
        const float* xp = x + (size_t)token * D_TOTAL + head * D_HEAD + gc * 8;
        float4 xa = *(const float4*)(xp);
        float4 xb = *(const float4*)(xp + 4);
        float s = scale[token];
        unsigned int u[4];
        u[0] = cvt_pk_bf16(xa.x * s, xa.y * s);
        u[1] = cvt_pk_bf16(xa.z * s, xa.w * s);
        u[2] = cvt_pk_bf16(xb.x * s, xb.y * s);
        u[3] = cvt_pk_bf16(xb.z * s, xb.w * s);
        int gsw = gc ^ (r & 7);
        *(uint4*)&sAct[r * HID + gsw * 8] = *(const uint4*)u;
    }
    __syncthreads();

    f32x16 acc[4][2];
    const int nb = wv * 64;              // this wave's N-chunk for stages 1-3

    // ---- stage 1: K=128 -> N=512 ----
    stage_gemm32<128, 4, 2>(sAct, wt0 + (size_t)head * HID * D_HEAD, lane, 0, nb, acc);
    __syncthreads();
    epi_gelu32<4, 2>(sAct, lane, 0, nb, acc);
    __syncthreads();

    // ---- stage 2: K=512 -> N=512 ----
    stage_gemm32<512, 4, 2>(sAct, wt1 + (size_t)head * HID * HID, lane, 0, nb, acc);
    __syncthreads();
    epi_gelu32<4, 2>(sAct, lane, 0, nb, acc);
    __syncthreads();

    // ---- stage 3: K=512 -> N=512 ----
    stage_gemm32<512, 4, 2>(sAct, wt2 + (size_t)head * HID * HID, lane, 0, nb, acc);
    __syncthreads();
    epi_gelu32<4, 2>(sAct, lane, 0, nb, acc);
    __syncthreads();

    // ---- stage 4: K=512 -> N=128, 16 32x32 tiles / 8 waves = 2 each ----
    const int nt4 = (wv & 3) * 32;        // col 32-block
    const int mt4 = (wv >> 2) * 64;       // first of two token 32-blocks
    f32x16 acc2[2][1];
    stage_gemm32<512, 2, 1>(sAct, wt3 + (size_t)head * D_HEAD * HID, lane, mt4, nt4, acc2);

    const int r31 = lane & 31;
    const int h   = lane >> 5;
#pragma unroll
    for (int mt = 0; mt < 2; ++mt) {
        const int token = tok0 + mt4 + mt * 32 + r31;
#pragma unroll
        for (int g = 0; g < 4; ++g) {
            const int col = head * D_HEAD + nt4 + 8 * g + 4 * h;
            float4_t v;
            v[0] = acc2[mt][0][4 * g + 0];
            v[1] = acc2[mt][0][4 * g + 1];
            v[2] = acc2[mt][0][4 * g + 2];
            v[3] = acc2[mt][0][4 * g + 3];
            *(float4_t*)&out[(size_t)token * D_TOTAL + col] = v;
        }
    }
}

// ---------------- host launcher ----------------
extern "C" void kernel_launch(void* const* d_in, const int* in_sizes, int n_in,
                              void* d_out, int out_size, void* d_ws, size_t ws_size,
                              hipStream_t stream)
{
    const float* x  = (const float*)d_in[0];
    const float* gw = (const float*)d_in[1];
    const float* w0 = (const float*)d_in[2];
    const float* w1 = (const float*)d_in[3];
    const float* w2 = (const float*)d_in[4];
    const float* w3 = (const float*)d_in[5];
    float* out = (float*)d_out;

    // workspace layout
    float* scale = (float*)d_ws;                                   // 64 KB
    unsigned short* wt0 = (unsigned short*)((char*)d_ws + 65536);  // [16][512][128]
    unsigned short* wt1 = wt0 + (size_t)N_HEAD * HID * D_HEAD;     // [16][512][512]
    unsigned short* wt2 = wt1 + (size_t)N_HEAD * HID * HID;        // [16][512][512]
    unsigned short* wt3 = wt2 + (size_t)N_HEAD * HID * HID;        // [16][128][512]

    // one prep launch: rms scales (4096 blocks) + 2560 transpose tiles
    prep_kernel<<<4096 + 2560, 256, 0, stream>>>(
        x, scale, w0, w1, w2, w3, gw, wt0, wt1, wt2, wt3);

    fused_chain_kernel<<<N_HEAD * (N_TOK / MT), 512, 0, stream>>>(
        x, scale, wt0, wt1, wt2, wt3, out);
}